// Round 10
// baseline (361.424 us; speedup 1.0000x reference)
//
#include <hip/hip_runtime.h>

// Problem constants (from reference)
#define NB      128
#define ND      8
#define NK      8
#define TLEN    512
#define NSTEPS  496

#define INVLN2f 1.44269504088896340736f

__device__ __forceinline__ float fexp(float x) { return __expf(x); }
__device__ __forceinline__ float flog(float x) { return __logf(x); }
__device__ __forceinline__ float frcp(float x) { return __builtin_amdgcn_rcpf(x); }
__device__ __forceinline__ float elur(float x) { return x > 0.f ? x : fexp(x) - 1.f; }

#if defined(__has_builtin)
#if __has_builtin(__builtin_amdgcn_exp2f)
#define fexp2(x) __builtin_amdgcn_exp2f(x)
#endif
#endif
#ifndef fexp2
#define fexp2(x) exp2f(x)
#endif

// DPP helpers. quad_perm 0xB1 = lane^1, 0x4E = lane^2, row_ror:4 acts as lane^4
// within a replicated-every-8 value; row_ror:N (0x120|N) rotates within 16-lane rows.
#define DPP_ROR4(v) __int_as_float(__builtin_amdgcn_mov_dpp(__float_as_int(v), 0x124, 0xF, 0xF, false))
#define DPP_X1(v)   __int_as_float(__builtin_amdgcn_mov_dpp(__float_as_int(v), 0xB1, 0xF, 0xF, false))
#define DPP_X2(v)   __int_as_float(__builtin_amdgcn_mov_dpp(__float_as_int(v), 0x4E, 0xF, 0xF, false))
#define DPP_RORN(v, ctrl) __int_as_float(__builtin_amdgcn_mov_dpp(__float_as_int(v), (ctrl), 0xF, 0xF, false))

#define RED8_MAX(m) { m = fmaxf(m, DPP_X1(m)); m = fmaxf(m, DPP_X2(m)); m = fmaxf(m, DPP_ROR4(m)); }
#define RED8_SUM(s) { s = s + DPP_X1(s); s = s + DPP_X2(s); s = s + DPP_ROR4(s); }

typedef unsigned int uint2v __attribute__((ext_vector_type(2)));
typedef float floatx2 __attribute__((ext_vector_type(2)));

#define PKFMA(a, b, c) __builtin_elementwise_fma((a), (b), (c))

__device__ __forceinline__ floatx2 f2(float t) { floatx2 r; r.x = t; r.y = t; return r; }

// v + v[lane^32] on all lanes, via VALU permlane32_swap (no DS pipe).
#if defined(__has_builtin)
#if __has_builtin(__builtin_amdgcn_permlane32_swap)
#define HAVE_PLSWAP 1
#endif
#if __has_builtin(__builtin_amdgcn_permlane16_swap)
#define HAVE_PL16SWAP 1
#endif
#endif

#ifdef HAVE_PLSWAP
__device__ __forceinline__ float xhalfsum(float v) {
    unsigned int u = __float_as_uint(v);
    uint2v r = __builtin_amdgcn_permlane32_swap(u, u, false, false);
    return __uint_as_float(r[0]) + __uint_as_float(r[1]);
}
#else
__device__ __forceinline__ float xhalfsum(float v) { return v + __shfl_xor(v, 32); }
#endif

// Raw lane^16 value (other 16-row). selr0 is the runtime-probed slot select.
#ifdef HAVE_PL16SWAP
#define XROW16R(v) ({                                                              \
    unsigned _u = __float_as_uint(v);                                              \
    uint2v _r = __builtin_amdgcn_permlane16_swap(_u, _u, false, false);            \
    __uint_as_float(selr0 ? _r[0] : _r[1]); })
#else
#define XROW16R(v) __uint_as_float((unsigned)__builtin_amdgcn_ds_swizzle(          \
                   (int)__float_as_uint(v), 0x401F))
#endif

// Layout-B fixup: rows 0,1 (lanes 0-31) keep own value; rows 2,3 take lane^16's.
#define TOB(v) ({                                                                  \
    float _v = (v);                                                                \
    float _o = XROW16R(_v);                                                        \
    (lane < 32) ? _v : _o; })

// Dual 16-term rotation dot (new-tap in .x, old-tap in .y). vB holds, at row
// slot s, h[jbase+s]. 8 chains x 2 FMA deep (chain hops: fma,fma + 3 tree adds
// = 5, one less than the 4-deep form). 15 row_ror DPP are independent off vB.
__device__ __forceinline__ floatx2 rotdot8c(float vB, const floatx2* __restrict__ wp) {
    float t1 = DPP_RORN(vB, 0x121), t2 = DPP_RORN(vB, 0x122), t3 = DPP_RORN(vB, 0x123);
    float t4 = DPP_RORN(vB, 0x124), t5 = DPP_RORN(vB, 0x125), t6 = DPP_RORN(vB, 0x126);
    float t7 = DPP_RORN(vB, 0x127), t8 = DPP_RORN(vB, 0x128), t9 = DPP_RORN(vB, 0x129);
    float tA = DPP_RORN(vB, 0x12A), tB = DPP_RORN(vB, 0x12B), tC = DPP_RORN(vB, 0x12C);
    float tD = DPP_RORN(vB, 0x12D), tE = DPP_RORN(vB, 0x12E), tF = DPP_RORN(vB, 0x12F);
    floatx2 a0 = wp[0] * f2(vB);
    floatx2 a1 = wp[1] * f2(t1);
    floatx2 a2 = wp[2] * f2(t2);
    floatx2 a3 = wp[3] * f2(t3);
    floatx2 a4 = wp[4] * f2(t4);
    floatx2 a5 = wp[5] * f2(t5);
    floatx2 a6 = wp[6] * f2(t6);
    floatx2 a7 = wp[7] * f2(t7);
    a0 = PKFMA(wp[8],  f2(t8), a0);
    a1 = PKFMA(wp[9],  f2(t9), a1);
    a2 = PKFMA(wp[10], f2(tA), a2);
    a3 = PKFMA(wp[11], f2(tB), a3);
    a4 = PKFMA(wp[12], f2(tC), a4);
    a5 = PKFMA(wp[13], f2(tD), a5);
    a6 = PKFMA(wp[14], f2(tE), a6);
    a7 = PKFMA(wp[15], f2(tF), a7);
    return ((a0 + a1) + (a2 + a3)) + ((a4 + a5) + (a6 + a7));
}

// One scan step. T-track layout: lanes 0-31 run the recurrence for channel c,
// lanes 32-63 for channel c^16 — so layer-0's output IS the layer-1 dot input
// ([lo,hi,hi,lo]) with NO on-chain TOB. The swapped track costs only per-lane
// swapped z-weights (wzT) plus an off-chain XROW16 of the x-part (exact: F,S,r2
// are channel-replicated). TOB remains for layers 2,3 (halfsum re-replicates).
// LDS reads (next x cols, next g2) prefetched one step ahead (cxa/cxb/G2R).
#define STEP(qv, S1, S2, S3, DO_OUT, PREFG)                                       \
  {                                                                               \
    const int q_ = (qv);                                                          \
    /* prefetch next step's LDS data (latency hidden under this step) */          \
    const float4* _nx = (const float4*)&xcol[q_ + 1 + tap][0];                    \
    float4 nxa = _nx[0], nxb = _nx[1];                                            \
    float g2n = 0.f;                                                              \
    if (PREFG) g2n = gls[(q_ - 14) * NK + o3];                                    \
    /* early, off-chain: T-track x-base of XZ(q_+1) from prefetched regs */       \
    float s0 = fmaf(wxr[0], cxa.x, fmaf(wxr[1], cxa.y, 0.f));                     \
    float s1 = fmaf(wxr[2], cxa.z, fmaf(wxr[3], cxa.w, 0.f));                     \
    float s2 = fmaf(wxr[4], cxb.x, fmaf(wxr[5], cxb.y, 0.f));                     \
    float s3 = fmaf(wxr[6], cxb.z, fmaf(wxr[7], cxb.w, 0.f));                     \
    float xpb  = xhalfsum((s0 + s1) + (s2 + s3)) + b0r;                           \
    float xpbB = XROW16R(xpb);                                                    \
    float XBASE = ((lane < 32) ? xpb : xpbB) + ZQ2;                               \
    /* layer 0: T-track value feeds layer 1 directly (no TOB) */                  \
    float o0v = elur(XZ);                                                         \
    /* layer 1 */                                                                 \
    floatx2 d1 = rotdot8c(o0v, w1p);                                              \
    float o1v = elur(xhalfsum(d1.x + P1[S1]));                                    \
    P1[S1] = b1h + d1.y;                                                          \
    /* layer 2 */                                                                 \
    float v1B = TOB(o1v);                                                         \
    floatx2 d2 = rotdot8c(v1B, w2p);                                              \
    float o2v = elur(xhalfsum(d2.x + P2[S2]));                                    \
    P2[S2] = b2h + d2.y;                                                          \
    /* layer 3 */                                                                 \
    float v2B = TOB(o2v);                                                         \
    floatx2 d3 = rotdot8c(v2B, w3p);                                              \
    float a3m = elur(xhalfsum(d3.x + P3[S3]));                                    \
    P3[S3] = b3h + d3.y;                                                          \
    if (DO_OUT) {                                                                 \
      /* feedback gumbel-softmax: single exp2, no max-sub */                      \
      float F = fexp2(fmaf(a3m, klog, G2R));                                      \
      float rt1 = DPP_RORN(F, 0x121), rt2 = DPP_RORN(F, 0x122);                   \
      float rt3 = DPP_RORN(F, 0x123), rt4 = DPP_RORN(F, 0x124);                   \
      float rt5 = DPP_RORN(F, 0x125), rt6 = DPP_RORN(F, 0x126);                   \
      float rt7 = DPP_RORN(F, 0x127);                                             \
      float S = ((F + rt1) + (rt2 + rt3)) + ((rt4 + rt5) + (rt6 + rt7));          \
      float r2 = frcp(S);                                                         \
      floatx2 na = wzT[0] * f2(F),   nb = wzT[1] * f2(rt1);                       \
      floatx2 nc = wzT[2] * f2(rt2), nd = wzT[3] * f2(rt3);                       \
      na = PKFMA(wzT[4], f2(rt4), na); nb = PKFMA(wzT[5], f2(rt5), nb);           \
      nc = PKFMA(wzT[6], f2(rt6), nc); nd = PKFMA(wzT[7], f2(rt7), nd);           \
      floatx2 zacc = (na + nb) + (nc + nd);                                       \
      ZN   = zacc.x * r2;   /* T-track wzn.y(q) -> XZ at q+1 */                   \
      ZQ2n = zacc.y * r2;   /* T-track wzo.y(q) -> XZ at q+2 */                   \
      /* off-path: log-softmax output (fills stall slots) */                      \
      float mx = a3m; RED8_MAX(mx);                                               \
      float e = fexp(a3m - mx);                                                   \
      float se = e; RED8_SUM(se);                                                 \
      float lse = mx + flog(se);                                                  \
      if (lane < 8) {                                                             \
        outg[zoff + lane * TLEN + q_ + 1]       = F * r2;                         \
        outg[qoff + lane * NSTEPS + (q_ - 15)]  = a3m - lse;                      \
      }                                                                           \
    }                                                                             \
    /* feedback tail: single add; rotate state; latch prefetches */               \
    XZ = XBASE + ZN;                                                              \
    ZQ2 = ZQ2n;                                                                   \
    cxa = nxa; cxb = nxb; G2R = g2n;                                              \
  }

__global__ __launch_bounds__(64, 1)
void regime_scan_kernel(const float* __restrict__ xg,
                        const float* __restrict__ tempg,
                        const float* __restrict__ ug,
                        const float* __restrict__ w0g,
                        const float* __restrict__ b0g,
                        const float* __restrict__ w1g,
                        const float* __restrict__ b1g,
                        const float* __restrict__ w2g,
                        const float* __restrict__ b2g,
                        const float* __restrict__ w3g,
                        const float* __restrict__ b3g,
                        float* __restrict__ outg)
{
    __shared__ __align__(16) float xcol[527][8];           // 16.9 KB
    __shared__ __align__(16) float gls[NSTEPS * NK + 8];   // 15.9 KB (g2, padded)

    const int lane = threadIdx.x;
    const int b    = blockIdx.x;
    const int c    = lane & 31;            // channel owned (layers 0-2)
    const int o3   = lane & 7;             // layer-3 channel owned
    const int tap  = (lane < 32) ? 1 : 0;  // x-park tap role
    const int s    = lane & 15;            // slot within 16-lane DPP row
    const int rowq = lane >> 4;            // DPP row 0..3
    // rows hold j-halves [lo,hi,hi,lo] (T-track for layer 1; TOB for 2,3)
    const int jbase = ((rowq ^ (rowq >> 1)) & 1) << 4;

    // ---- runtime probe (uniform): row_ror direction on this HW ----
    int dir;
    {
        int l15 = lane & 15;
        int rr1 = __builtin_amdgcn_mov_dpp(l15, 0x121, 0xF, 0xF, false); // row_ror:1
        dir = (rr1 == ((l15 + 1) & 15)) ? 1 : -1;
    }
    // ---- runtime probe (per-lane): which permlane16_swap slot is lane^16 ----
    int selr0 = 0;
#ifdef HAVE_PL16SWAP
    {
        unsigned li = (unsigned)lane;
        uint2v pr = __builtin_amdgcn_permlane16_swap(li, li, false, false);
        selr0 = (pr[0] == (li ^ 16u)) ? 1 : 0;
    }
#endif
    (void)selr0;

    // ---- per-lane weights ----
    // layer0 z weights, 8-group ROTATION order, packed (new=.x, old=.y),
    // T-track: upper lanes carry channel c^16's weights (exact-equivalent to
    // TOB(XZ) since F/S/r2 are channel-replicated).
    const int cT = (lane < 32) ? c : (c ^ 16);
    floatx2 wzT[8];
    #pragma unroll
    for (int r = 0; r < 8; ++r) {
        int ch = (o3 + dir * r) & 7;
        wzT[r].x = w0g[cT * 32 + (8 + ch) * 2 + 1];
        wzT[r].y = w0g[cT * 32 + (8 + ch) * 2 + 0];
    }
    // layer0 x weights: T-track channel, per-tap role (xpb swapped separately,
    // so wxr stays on channel c — the swap happens after halfsum via XROW16R).
    float wxr[8];
    #pragma unroll
    for (int d = 0; d < 8; ++d) wxr[d] = w0g[c * 32 + d * 2 + tap];
    // layers 1-3: dual (new,old) weights in 16-row ROTATION order
    floatx2 w1p[16], w2p[16], w3p[16];
    #pragma unroll
    for (int r = 0; r < 16; ++r) {
        int jj = jbase + ((s + dir * r) & 15);
        w1p[r].x = w1g[c  * 64 + jj * 2 + 1];
        w1p[r].y = w1g[c  * 64 + jj * 2 + 0];
        w2p[r].x = w2g[c  * 64 + jj * 2 + 1];
        w2p[r].y = w2g[c  * 64 + jj * 2 + 0];
        w3p[r].x = w3g[o3 * 64 + jj * 2 + 1];
        w3p[r].y = w3g[o3 * 64 + jj * 2 + 0];
    }
    const float b0r  = b0g[c];
    const float b1h  = 0.5f * b1g[c];      // half-bias: completed by xhalfsum
    const float b2h  = 0.5f * b2g[c];
    const float b3h  = 0.5f * b3g[o3];
    const float tinv = frcp(tempg[0]);
    const float klog = tinv * INVLN2f;     // a3 coefficient in exp2 domain

    // ---- prologue: x columns ----
    if (lane < 15) {
        #pragma unroll
        for (int d = 0; d < ND; ++d) xcol[lane][d] = 0.f;
    }
    const float* xb = xg + b * (ND * TLEN);
    for (int t = lane; t < TLEN; t += 64) {
        #pragma unroll
        for (int d = 0; d < ND; ++d) xcol[15 + t][d] = xb[d * TLEN + t];
    }
    // ---- prologue: Gumbel noise, pre-scaled: g2 = g * tinv / ln2 ----
    for (int idx = lane; idx < NSTEPS * NK; idx += 64) {
        int st = idx >> 3, k = idx & 7;
        float uu = ug[st * (NB * NK) + b * NK + k];
        float g  = -flog(-flog(uu + 1e-10f) + 1e-10f);
        gls[idx] = g * klog;
    }
    // ---- z_all[:, :, 0:16] = 0 ----
    const int zoff = b * (NK * TLEN);
    const int qoff = NB * NK * TLEN + b * (NK * NSTEPS);
    for (int idx = lane; idx < NK * 16; idx += 64) {
        outg[zoff + (idx >> 4) * TLEN + (idx & 15)] = 0.f;
    }

    // ---- state ----
    float P1[2] = { b1h, b1h };
    float P2[4] = { b2h, b2h, b2h, b2h };
    float P3[8];
    #pragma unroll
    for (int k = 0; k < 8; ++k) P3[k] = b3h;
    float ZQ2 = 0.f, ZQ2n = 0.f, ZN = 0.f;
    float G2R = 0.f;
    float XZ;
    {
        const float4* xq = (const float4*)&xcol[tap][0];
        float4 xa = xq[0], xbv = xq[1];
        float s0 = fmaf(wxr[0], xa.x, fmaf(wxr[1], xa.y, 0.f));
        float s1 = fmaf(wxr[2], xa.z, fmaf(wxr[3], xa.w, 0.f));
        float s2 = fmaf(wxr[4], xbv.x, fmaf(wxr[5], xbv.y, 0.f));
        float s3 = fmaf(wxr[6], xbv.z, fmaf(wxr[7], xbv.w, 0.f));
        float xpb0 = xhalfsum((s0 + s1) + (s2 + s3)) + b0r;
        float xpb0B = XROW16R(xpb0);
        XZ = (lane < 32) ? xpb0 : xpb0B;   // T-track; z = 0 at start
    }
    // prefetch registers for STEP(1)'s park: xcol[1+tap]
    float4 cxa, cxb;
    {
        const float4* cx = (const float4*)&xcol[1 + tap][0];
        cxa = cx[0]; cxb = cx[1];
    }

    // ---- warmup q=1..14 (z stays zero; g2 prefetch only at q=14) ----
    #pragma unroll
    for (int q = 1; q <= 14; ++q) STEP(q, q & 1, q & 3, q & 7, 0, (q == 14));

    // ---- main loop q=15..510, unrolled by 8 ----
    for (int qb = 15; qb <= 503; qb += 8) {
        #pragma unroll
        for (int u = 0; u < 8; ++u) {
            STEP(qb + u, (15 + u) & 1, (15 + u) & 3, (15 + u) & 7, 1, 1);
        }
    }
}

extern "C" void kernel_launch(void* const* d_in, const int* in_sizes, int n_in,
                              void* d_out, int out_size, void* d_ws, size_t ws_size,
                              hipStream_t stream) {
    (void)in_sizes; (void)n_in; (void)out_size; (void)d_ws; (void)ws_size;
    regime_scan_kernel<<<dim3(NB), dim3(64), 0, stream>>>(
        (const float*)d_in[0],   // x
        (const float*)d_in[1],   // temp
        (const float*)d_in[2],   // u
        (const float*)d_in[3],   // w0
        (const float*)d_in[4],   // b0
        (const float*)d_in[5],   // w1
        (const float*)d_in[6],   // b1
        (const float*)d_in[7],   // w2
        (const float*)d_in[8],   // b2
        (const float*)d_in[9],   // w3
        (const float*)d_in[10],  // b3
        (float*)d_out);
}

// Round 11
// 350.677 us; speedup vs baseline: 1.0306x; 1.0306x over previous
//
#include <hip/hip_runtime.h>

// Problem constants (from reference)
#define NB      128
#define ND      8
#define NK      8
#define TLEN    512
#define NSTEPS  496

#define INVLN2f 1.44269504088896340736f

__device__ __forceinline__ float fexp(float x) { return __expf(x); }
__device__ __forceinline__ float flog(float x) { return __logf(x); }
__device__ __forceinline__ float frcp(float x) { return __builtin_amdgcn_rcpf(x); }
__device__ __forceinline__ float elur(float x) { return x > 0.f ? x : fexp(x) - 1.f; }

#if defined(__has_builtin)
#if __has_builtin(__builtin_amdgcn_exp2f)
#define fexp2(x) __builtin_amdgcn_exp2f(x)
#endif
#endif
#ifndef fexp2
#define fexp2(x) exp2f(x)
#endif

// DPP helpers. quad_perm 0xB1 = lane^1, 0x4E = lane^2, row_ror:4 acts as lane^4
// within a replicated-every-8 value; row_ror:N (0x120|N) rotates within 16-lane rows.
#define DPP_ROR4(v) __int_as_float(__builtin_amdgcn_mov_dpp(__float_as_int(v), 0x124, 0xF, 0xF, false))
#define DPP_X1(v)   __int_as_float(__builtin_amdgcn_mov_dpp(__float_as_int(v), 0xB1, 0xF, 0xF, false))
#define DPP_X2(v)   __int_as_float(__builtin_amdgcn_mov_dpp(__float_as_int(v), 0x4E, 0xF, 0xF, false))
#define DPP_RORN(v, ctrl) __int_as_float(__builtin_amdgcn_mov_dpp(__float_as_int(v), (ctrl), 0xF, 0xF, false))

#define RED8_MAX(m) { m = fmaxf(m, DPP_X1(m)); m = fmaxf(m, DPP_X2(m)); m = fmaxf(m, DPP_ROR4(m)); }
#define RED8_SUM(s) { s = s + DPP_X1(s); s = s + DPP_X2(s); s = s + DPP_ROR4(s); }

typedef unsigned int uint2v __attribute__((ext_vector_type(2)));
typedef float floatx2 __attribute__((ext_vector_type(2)));

#define PKFMA(a, b, c) __builtin_elementwise_fma((a), (b), (c))

__device__ __forceinline__ floatx2 f2(float t) { floatx2 r; r.x = t; r.y = t; return r; }

// v + v[lane^32] on all lanes, via VALU permlane32_swap (no DS pipe).
#if defined(__has_builtin)
#if __has_builtin(__builtin_amdgcn_permlane32_swap)
#define HAVE_PLSWAP 1
#endif
#if __has_builtin(__builtin_amdgcn_permlane16_swap)
#define HAVE_PL16SWAP 1
#endif
#endif

#ifdef HAVE_PLSWAP
__device__ __forceinline__ float xhalfsum(float v) {
    unsigned int u = __float_as_uint(v);
    uint2v r = __builtin_amdgcn_permlane32_swap(u, u, false, false);
    return __uint_as_float(r[0]) + __uint_as_float(r[1]);
}
#else
__device__ __forceinline__ float xhalfsum(float v) { return v + __shfl_xor(v, 32); }
#endif

// Layout-B fixup: rows 0,1 (lanes 0-31) keep own value; rows 2,3 take lane^16's.
#ifdef HAVE_PL16SWAP
#define TOB(v) ({                                                                  \
    float _v = (v);                                                                \
    unsigned _u = __float_as_uint(_v);                                             \
    uint2v _r = __builtin_amdgcn_permlane16_swap(_u, _u, false, false);            \
    float _o = __uint_as_float(selr0 ? _r[0] : _r[1]);                             \
    (lane < 32) ? _v : _o; })
#else
#define TOB(v) ({                                                                  \
    float _v = (v);                                                                \
    float _o = __uint_as_float((unsigned)__builtin_amdgcn_ds_swizzle(              \
                   (int)__float_as_uint(_v), 0x401F));                             \
    (lane < 32) ? _v : _o; })
#endif

// Dual 16-term rotation dot (new-tap in .x, old-tap in .y). vB holds, at row
// slot s, h[jbase+s]; the 15 row_ror DPP movs are independent (all off vB).
// Weights pre-ordered per lane so wp[r] pairs with rotation r.
__device__ __forceinline__ floatx2 rotdot16x2p(float vB, const floatx2* __restrict__ wp) {
    float t1 = DPP_RORN(vB, 0x121), t2 = DPP_RORN(vB, 0x122), t3 = DPP_RORN(vB, 0x123);
    float t4 = DPP_RORN(vB, 0x124), t5 = DPP_RORN(vB, 0x125), t6 = DPP_RORN(vB, 0x126);
    float t7 = DPP_RORN(vB, 0x127), t8 = DPP_RORN(vB, 0x128), t9 = DPP_RORN(vB, 0x129);
    float tA = DPP_RORN(vB, 0x12A), tB = DPP_RORN(vB, 0x12B), tC = DPP_RORN(vB, 0x12C);
    float tD = DPP_RORN(vB, 0x12D), tE = DPP_RORN(vB, 0x12E), tF = DPP_RORN(vB, 0x12F);
    floatx2 a0 = wp[0] * f2(vB);
    floatx2 a1 = wp[1] * f2(t1);
    floatx2 a2 = wp[2] * f2(t2);
    floatx2 a3 = wp[3] * f2(t3);
    a0 = PKFMA(wp[4],  f2(t4), a0);
    a1 = PKFMA(wp[5],  f2(t5), a1);
    a2 = PKFMA(wp[6],  f2(t6), a2);
    a3 = PKFMA(wp[7],  f2(t7), a3);
    a0 = PKFMA(wp[8],  f2(t8), a0);
    a1 = PKFMA(wp[9],  f2(t9), a1);
    a2 = PKFMA(wp[10], f2(tA), a2);
    a3 = PKFMA(wp[11], f2(tB), a3);
    a0 = PKFMA(wp[12], f2(tC), a0);
    a1 = PKFMA(wp[13], f2(tD), a1);
    a2 = PKFMA(wp[14], f2(tE), a2);
    a3 = PKFMA(wp[15], f2(tF), a3);
    return (a0 + a1) + (a2 + a3);
}

// One scan step. All per-step LDS reads (next x cols, next g2) are PREFETCHED
// one full step ahead into registers (cxa/cxb/G2R), so no lgkm wait is ever on
// the critical chain. XBASE (x-part of XZ(q+1)) is computed at step START from
// already-available registers; the feedback tail only does XZ = XBASE + ZN.
// PREFG: whether to prefetch g2 for q+1 (only valid from q=14 on).
#define STEP(qv, S1, S2, S3, DO_OUT, PREFG)                                       \
  {                                                                               \
    const int q_ = (qv);                                                          \
    /* prefetch next step's LDS data (latency hidden under this step) */          \
    const float4* _nx = (const float4*)&xcol[q_ + 1 + tap][0];                    \
    float4 nxa = _nx[0], nxb = _nx[1];                                            \
    float g2n = 0.f;                                                              \
    if (PREFG) g2n = gls[(q_ - 14) * NK + o3];                                    \
    /* early: x-base of XZ(q_+1) from regs prefetched last step */                \
    float s0 = fmaf(wxr[0], cxa.x, fmaf(wxr[1], cxa.y, 0.f));                     \
    float s1 = fmaf(wxr[2], cxa.z, fmaf(wxr[3], cxa.w, 0.f));                     \
    float s2 = fmaf(wxr[4], cxb.x, fmaf(wxr[5], cxb.y, 0.f));                     \
    float s3 = fmaf(wxr[6], cxb.z, fmaf(wxr[7], cxb.w, 0.f));                     \
    float XBASE = (xhalfsum((s0 + s1) + (s2 + s3)) + b0r) + ZQ2;                  \
    /* layer 0: all contributions pre-folded into XZ */                           \
    float o0v = elur(XZ);                                                         \
    /* layer 1 */                                                                 \
    float v0B = TOB(o0v);                                                         \
    floatx2 d1 = rotdot16x2p(v0B, w1p);                                           \
    float o1v = elur(xhalfsum(d1.x + P1[S1]));                                    \
    P1[S1] = b1h + d1.y;                                                          \
    /* layer 2 */                                                                 \
    float v1B = TOB(o1v);                                                         \
    floatx2 d2 = rotdot16x2p(v1B, w2p);                                           \
    float o2v = elur(xhalfsum(d2.x + P2[S2]));                                    \
    P2[S2] = b2h + d2.y;                                                          \
    /* layer 3 */                                                                 \
    float v2B = TOB(o2v);                                                         \
    floatx2 d3 = rotdot16x2p(v2B, w3p);                                           \
    float a3m = elur(xhalfsum(d3.x + P3[S3]));                                    \
    P3[S3] = b3h + d3.y;                                                          \
    if (DO_OUT) {                                                                 \
      /* feedback gumbel-softmax: single exp2, no max-sub */                      \
      float F = fexp2(fmaf(a3m, klog, G2R));                                      \
      float rt1 = DPP_RORN(F, 0x121), rt2 = DPP_RORN(F, 0x122);                   \
      float rt3 = DPP_RORN(F, 0x123), rt4 = DPP_RORN(F, 0x124);                   \
      float rt5 = DPP_RORN(F, 0x125), rt6 = DPP_RORN(F, 0x126);                   \
      float rt7 = DPP_RORN(F, 0x127);                                             \
      float S = ((F + rt1) + (rt2 + rt3)) + ((rt4 + rt5) + (rt6 + rt7));          \
      float r2 = frcp(S);                                                         \
      floatx2 na = wz[0] * f2(F),   nb = wz[1] * f2(rt1);                         \
      floatx2 nc = wz[2] * f2(rt2), nd = wz[3] * f2(rt3);                         \
      na = PKFMA(wz[4], f2(rt4), na); nb = PKFMA(wz[5], f2(rt5), nb);             \
      nc = PKFMA(wz[6], f2(rt6), nc); nd = PKFMA(wz[7], f2(rt7), nd);             \
      floatx2 zacc = (na + nb) + (nc + nd);                                       \
      ZN   = zacc.x * r2;   /* wzn.y(q) -> XZ at q+1 */                           \
      ZQ2n = zacc.y * r2;   /* wzo.y(q) -> XZ at q+2 */                           \
      /* off-path: log-softmax output (fills stall slots) */                      \
      float mx = a3m; RED8_MAX(mx);                                               \
      float e = fexp(a3m - mx);                                                   \
      float se = e; RED8_SUM(se);                                                 \
      float lse = mx + flog(se);                                                  \
      if (lane < 8) {                                                             \
        outg[zoff + lane * TLEN + q_ + 1]       = F * r2;                         \
        outg[qoff + lane * NSTEPS + (q_ - 15)]  = a3m - lse;                      \
      }                                                                           \
    }                                                                             \
    /* feedback tail: single add; rotate state; latch prefetches */               \
    XZ = XBASE + ZN;                                                              \
    ZQ2 = ZQ2n;                                                                   \
    cxa = nxa; cxb = nxb; G2R = g2n;                                              \
  }

__global__ __launch_bounds__(64, 1)
void regime_scan_kernel(const float* __restrict__ xg,
                        const float* __restrict__ tempg,
                        const float* __restrict__ ug,
                        const float* __restrict__ w0g,
                        const float* __restrict__ b0g,
                        const float* __restrict__ w1g,
                        const float* __restrict__ b1g,
                        const float* __restrict__ w2g,
                        const float* __restrict__ b2g,
                        const float* __restrict__ w3g,
                        const float* __restrict__ b3g,
                        float* __restrict__ outg)
{
    __shared__ __align__(16) float xcol[527][8];           // 16.9 KB
    __shared__ __align__(16) float gls[NSTEPS * NK + 8];   // 15.9 KB (g2, padded)

    const int lane = threadIdx.x;
    const int b    = blockIdx.x;
    const int c    = lane & 31;            // channel owned (layers 0-2)
    const int o3   = lane & 7;             // layer-3 channel owned
    const int tap  = (lane < 32) ? 1 : 0;  // x-park tap role
    const int s    = lane & 15;            // slot within 16-lane DPP row
    const int rowq = lane >> 4;            // DPP row 0..3
    // rows hold j-halves [lo,hi,hi,lo] after the TOB fixup
    const int jbase = ((rowq ^ (rowq >> 1)) & 1) << 4;

    // ---- runtime probe (uniform): row_ror direction on this HW ----
    int dir;
    {
        int l15 = lane & 15;
        int rr1 = __builtin_amdgcn_mov_dpp(l15, 0x121, 0xF, 0xF, false); // row_ror:1
        dir = (rr1 == ((l15 + 1) & 15)) ? 1 : -1;
    }
    // ---- runtime probe (per-lane): which permlane16_swap slot is lane^16 ----
    int selr0 = 0;
#ifdef HAVE_PL16SWAP
    {
        unsigned li = (unsigned)lane;
        uint2v pr = __builtin_amdgcn_permlane16_swap(li, li, false, false);
        selr0 = (pr[0] == (li ^ 16u)) ? 1 : 0;
    }
#endif
    (void)selr0;

    // ---- per-lane weights ----
    // layer0 z weights in 8-group ROTATION order, packed (new=.x, old=.y)
    floatx2 wz[8];
    #pragma unroll
    for (int r = 0; r < 8; ++r) {
        int ch = (o3 + dir * r) & 7;
        wz[r].x = w0g[c * 32 + (8 + ch) * 2 + 1];
        wz[r].y = w0g[c * 32 + (8 + ch) * 2 + 0];
    }
    float wxr[8];
    #pragma unroll
    for (int d = 0; d < 8; ++d) wxr[d] = w0g[c * 32 + d * 2 + tap];
    // layers 1-3: dual (new,old) weights in 16-row ROTATION order
    floatx2 w1p[16], w2p[16], w3p[16];
    #pragma unroll
    for (int r = 0; r < 16; ++r) {
        int jj = jbase + ((s + dir * r) & 15);
        w1p[r].x = w1g[c  * 64 + jj * 2 + 1];
        w1p[r].y = w1g[c  * 64 + jj * 2 + 0];
        w2p[r].x = w2g[c  * 64 + jj * 2 + 1];
        w2p[r].y = w2g[c  * 64 + jj * 2 + 0];
        w3p[r].x = w3g[o3 * 64 + jj * 2 + 1];
        w3p[r].y = w3g[o3 * 64 + jj * 2 + 0];
    }
    const float b0r  = b0g[c];
    const float b1h  = 0.5f * b1g[c];      // half-bias: completed by xhalfsum
    const float b2h  = 0.5f * b2g[c];
    const float b3h  = 0.5f * b3g[o3];
    const float tinv = frcp(tempg[0]);
    const float klog = tinv * INVLN2f;     // a3 coefficient in exp2 domain

    // ---- prologue: x columns ----
    if (lane < 15) {
        #pragma unroll
        for (int d = 0; d < ND; ++d) xcol[lane][d] = 0.f;
    }
    const float* xb = xg + b * (ND * TLEN);
    for (int t = lane; t < TLEN; t += 64) {
        #pragma unroll
        for (int d = 0; d < ND; ++d) xcol[15 + t][d] = xb[d * TLEN + t];
    }
    // ---- prologue: Gumbel noise, pre-scaled: g2 = g * tinv / ln2 ----
    for (int idx = lane; idx < NSTEPS * NK; idx += 64) {
        int st = idx >> 3, k = idx & 7;
        float uu = ug[st * (NB * NK) + b * NK + k];
        float g  = -flog(-flog(uu + 1e-10f) + 1e-10f);
        gls[idx] = g * klog;
    }
    // ---- z_all[:, :, 0:16] = 0 ----
    const int zoff = b * (NK * TLEN);
    const int qoff = NB * NK * TLEN + b * (NK * NSTEPS);
    for (int idx = lane; idx < NK * 16; idx += 64) {
        outg[zoff + (idx >> 4) * TLEN + (idx & 15)] = 0.f;
    }

    // ---- state ----
    float P1[2] = { b1h, b1h };
    float P2[4] = { b2h, b2h, b2h, b2h };
    float P3[8];
    #pragma unroll
    for (int k = 0; k < 8; ++k) P3[k] = b3h;
    float ZQ2 = 0.f, ZQ2n = 0.f, ZN = 0.f;
    float G2R = 0.f;
    float XZ;
    {
        const float4* xq = (const float4*)&xcol[tap][0];
        float4 xa = xq[0], xbv = xq[1];
        float s0 = fmaf(wxr[0], xa.x, fmaf(wxr[1], xa.y, 0.f));
        float s1 = fmaf(wxr[2], xa.z, fmaf(wxr[3], xa.w, 0.f));
        float s2 = fmaf(wxr[4], xbv.x, fmaf(wxr[5], xbv.y, 0.f));
        float s3 = fmaf(wxr[6], xbv.z, fmaf(wxr[7], xbv.w, 0.f));
        XZ = xhalfsum((s0 + s1) + (s2 + s3)) + b0r;   // z = 0 at start
    }
    // prefetch registers for STEP(1)'s park: xcol[1+tap]
    float4 cxa, cxb;
    {
        const float4* cx = (const float4*)&xcol[1 + tap][0];
        cxa = cx[0]; cxb = cx[1];
    }

    // ---- warmup q=1..14 (z stays zero; g2 prefetch only at q=14) ----
    #pragma unroll
    for (int q = 1; q <= 14; ++q) STEP(q, q & 1, q & 3, q & 7, 0, (q == 14));

    // ---- main loop q=15..510, unrolled by 8 ----
    for (int qb = 15; qb <= 503; qb += 8) {
        #pragma unroll
        for (int u = 0; u < 8; ++u) {
            STEP(qb + u, (15 + u) & 1, (15 + u) & 3, (15 + u) & 7, 1, 1);
        }
    }
}

extern "C" void kernel_launch(void* const* d_in, const int* in_sizes, int n_in,
                              void* d_out, int out_size, void* d_ws, size_t ws_size,
                              hipStream_t stream) {
    (void)in_sizes; (void)n_in; (void)out_size; (void)d_ws; (void)ws_size;
    regime_scan_kernel<<<dim3(NB), dim3(64), 0, stream>>>(
        (const float*)d_in[0],   // x
        (const float*)d_in[1],   // temp
        (const float*)d_in[2],   // u
        (const float*)d_in[3],   // w0
        (const float*)d_in[4],   // b0
        (const float*)d_in[5],   // w1
        (const float*)d_in[6],   // b1
        (const float*)d_in[7],   // w2
        (const float*)d_in[8],   // b2
        (const float*)d_in[9],   // w3
        (const float*)d_in[10],  // b3
        (float*)d_out);
}